// Round 5
// baseline (940.993 us; speedup 1.0000x reference)
//
#include <hip/hip_runtime.h>
#include <math.h>

#define BS 8192
#define SL 49
#define FDIM 11
#define ROWS (BS*SL)

typedef float v2f __attribute__((ext_vector_type(2)));

__device__ __forceinline__ v2f mk2(float a, float b) { v2f r; r.x = a; r.y = b; return r; }
__device__ __forceinline__ v2f pkfma(v2f a, v2f b, v2f c) {
  return __builtin_elementwise_fma(a, b, c);   // lowers to v_pk_fma_f32 on gfx90a+
}

__device__ __forceinline__ float tanhshrink_f(float x) {
  // x - tanh(x), tanh = 1 - 2/(e^{2x}+1). Robust at +-inf of exp.
  float e = __expf(2.f * x);
  return (x - 1.f) + __fdividef(2.f, e + 1.f);
}

// ---------------- BN stats: sum / sumsq over (BS,SL) for features {0..7,10} ----
__global__ __launch_bounds__(256) void k_stats(const float* __restrict__ inp,
                                               double* __restrict__ gsum) {
  const int nblk = gridDim.x;
  const int per = (ROWS + nblk - 1) / nblk;
  const int r0 = blockIdx.x * per;
  int r1 = r0 + per; if (r1 > ROWS) r1 = ROWS;
  float s[9], q[9];
#pragma unroll
  for (int j = 0; j < 9; ++j) { s[j] = 0.f; q[j] = 0.f; }
  for (int r = r0 + threadIdx.x; r < r1; r += 256) {
    const float* row = inp + r * FDIM;
#pragma unroll
    for (int j = 0; j < 9; ++j) {
      float v = row[j < 8 ? j : 10];
      s[j] += v; q[j] += v * v;
    }
  }
#pragma unroll
  for (int j = 0; j < 9; ++j) {
    for (int off = 32; off; off >>= 1) {
      s[j] += __shfl_down(s[j], off);
      q[j] += __shfl_down(q[j], off);
    }
  }
  __shared__ float red[4][18];
  const int wid = threadIdx.x >> 6;
  const int lane = threadIdx.x & 63;
  if (lane == 0) {
#pragma unroll
    for (int j = 0; j < 9; ++j) { red[wid][j] = s[j]; red[wid][9 + j] = q[j]; }
  }
  __syncthreads();
  if (threadIdx.x < 18) {
    float t = red[0][threadIdx.x] + red[1][threadIdx.x] +
              red[2][threadIdx.x] + red[3][threadIdx.x];
    atomicAdd(&gsum[threadIdx.x], (double)t);
  }
}

// ------- pack kernel (parallel, no gsum dependency): weight relayouts -------
// xw1T[c][k] (64x8); we2[s][kc][c][kk] = W2[4kc+kk][c]; wk4[ls][kc][c][kk].
__global__ __launch_bounds__(256) void k_pack(const float* __restrict__ xe_w1,
                          const float* __restrict__ xe_w2,
                          const float* __restrict__ ye_w2,
                          const float* __restrict__ Wk,
                          float* __restrict__ xw1T,
                          float* __restrict__ we2,
                          float* __restrict__ wk4) {
  int gid = blockIdx.x * 256 + threadIdx.x;   // 8192 threads
  if (gid < 512) { int cc = gid >> 3, k = gid & 7; xw1T[gid] = xe_w1[k * 64 + cc]; }
  {
    int i = gid;  // 8192 elements, one each
    int ss = i >> 12, r = i & 4095, kc = r >> 8, cc = (r >> 2) & 63, kk = r & 3;
    const float* W2 = ss ? ye_w2 : xe_w2;
    we2[i] = W2[(4 * kc + kk) * 64 + cc];
  }
  for (int i = gid; i < 16384; i += 8192) {
    int ls = i >> 12, r = i & 4095, kc = r >> 8, cc = (r >> 2) & 63, kk = r & 3;
    wk4[i] = Wk[ls * 4096 + (4 * kc + kk) * 64 + cc];
  }
}

// ---------------- finalize: BN params + layer-0 q (needs gsum) ----------------
__global__ __launch_bounds__(256) void k_finalize(const double* __restrict__ gsum,
                           const float* __restrict__ gamma,
                           const float* __restrict__ beta,
                           const float* __restrict__ hidden,
                           const float* __restrict__ Wq,
                           float* __restrict__ bnp,
                           float* __restrict__ q0g) {
  int tid = threadIdx.x;
  if (tid < 9) {
    const double N = (double)ROWS;
    double mean = gsum[tid] / N;
    double msq  = gsum[9 + tid] / N;
    float var = (float)(msq - mean * mean);
    float sc = gamma[tid] / sqrtf(var + 1e-5f);
    bnp[tid] = sc;
    bnp[9 + tid] = beta[tid] - (float)mean * sc;
  }
  // q0[s][i][c] = sum_k hidden[i][k] * Wq[l=0,s][k][c]
  int s = tid >> 7, i2 = (tid >> 6) & 1, c = tid & 63;
  const float* W = Wq + (s << 12);
#pragma unroll
  for (int ii = 0; ii < 2; ++ii) {
    int i = i2 + 2 * ii;
    float a = 0.f;
    for (int k = 0; k < 64; ++k) a += hidden[i * 64 + k] * W[k * 64 + c];
    q0g[s * 256 + i * 64 + c] = a;
  }
}

// ---------------- mega kernel: one block per (batch, stream) ----------------
// Round-4 structure + packed-fp32 math: all dense FMA loops expressed as
// float2 fma (v_pk_fma_f32, 2 fp32 FLOP/inst) -> ~half the VALU issue slots.
// Pairing is always along an axis where both elements are register-adjacent.
__global__ __launch_bounds__(256, 4) void k_mega(
    const float* __restrict__ inp, const float* __restrict__ dists,
    const float* __restrict__ bnp, const float* __restrict__ q0g,
    const float* __restrict__ xw1T, const float* __restrict__ xe_b1,
    const float* __restrict__ we2, const float* __restrict__ xe_b2,
    const float* __restrict__ ye_w1, const float* __restrict__ ye_b1,
    const float* __restrict__ ye_b2,
    const float* __restrict__ learnable_y, const float* __restrict__ hidden_tokens,
    const float* __restrict__ Wq, const float* __restrict__ wk4,
    const float* __restrict__ Wv, const float* __restrict__ Wo,
    const float* __restrict__ Wq2, const float* __restrict__ Wk2,
    const float* __restrict__ Wv2, const float* __restrict__ Wo2,
    float* __restrict__ enc)
{
  __shared__ float raw[49][12];
  __shared__ float cs8T[8][52];   // [p][t]: per-lane distinct reads
  __shared__ float embs[49 * 68]; // emb, stride 68
  __shared__ float KB[49][68];    // h1, then K (rope'd), then T, then k2/v2
  __shared__ float scb[32][52];   // softmax probs
  __shared__ float Hs[4][64];
  __shared__ float qb[4][64];
  __shared__ float db[48];
  __shared__ float bnl[18];
  __shared__ float q2[64];
  __shared__ float o1[64];
  __shared__ float a2[32];

  const int tid  = threadIdx.x;
  const int lane = tid & 63;
  const int grp  = tid >> 6;
  const int wg   = __builtin_amdgcn_readfirstlane(grp);  // provably wave-uniform
  const int b    = blockIdx.x >> 1;
  const int s    = blockIdx.x & 1;
  const float scale = 0.35355339059327373f;  // 1/sqrt(8)

  // ---- load input rows, bn params, dists
  for (int i = tid; i < 49 * FDIM; i += 256) raw[i / FDIM][i % FDIM] = inp[b * (49*FDIM) + i];
  if (tid < 18) bnl[tid] = bnp[tid];
  if (tid >= 64 && tid < 112) db[tid - 64] = dists[b * 49 + (tid - 64)];
  __syncthreads();   // B1

  // ---- rope trig from RAW features 8,9 ; BN features {0..7,10} in place
  if (tid < 49) {
    float x = raw[tid][8], y = raw[tid][9];
    cs8T[0][tid] = cosf(10.f * x); cs8T[1][tid] = cosf(10.f * y);
    cs8T[2][tid] = cosf(x);        cs8T[3][tid] = cosf(y);
    cs8T[4][tid] = sinf(10.f * x); cs8T[5][tid] = sinf(10.f * y);
    cs8T[6][tid] = sinf(x);        cs8T[7][tid] = sinf(y);
  }
  for (int i = tid; i < 441; i += 256) {   // 49*9
    int t = i / 9, j = i - t * 9;
    int f = (j < 8) ? j : 10;
    raw[t][f] = raw[t][f] * bnl[j] + bnl[9 + j];
  }
  __syncthreads();   // B2

  if (s == 0 && tid < 10) enc[b * 138 + 128 + tid] = raw[48][tid];

  // ---- embed layer 1 -> KB (h1). lane=row, wave wg = cols 16wg..16wg+15
  if (s == 0) {
    if (lane < 49) {
      float4 r0 = *(const float4*)&raw[lane][0];
      float4 r1 = *(const float4*)&raw[lane][4];
      const float* w = xw1T + wg * 128;   // 16 cols x 8 k, contiguous, uniform
      float h[16];
#pragma unroll
      for (int ci = 0; ci < 16; ++ci) {
        v2f h2 = mk2(0.f, 0.f);
        h2 = pkfma(mk2(r0.x, r0.y), *(const v2f*)&w[ci*8+0], h2);
        h2 = pkfma(mk2(r0.z, r0.w), *(const v2f*)&w[ci*8+2], h2);
        h2 = pkfma(mk2(r1.x, r1.y), *(const v2f*)&w[ci*8+4], h2);
        h2 = pkfma(mk2(r1.z, r1.w), *(const v2f*)&w[ci*8+6], h2);
        h[ci] = tanhshrink_f(xe_b1[wg * 16 + ci] + h2.x + h2.y);
      }
#pragma unroll
      for (int i = 0; i < 4; ++i)
        *(float4*)&KB[lane][wg * 16 + 4 * i] = make_float4(h[4*i], h[4*i+1], h[4*i+2], h[4*i+3]);
    }
  } else {
    if (lane < 48) {
      float ry = raw[lane][10];
      float h[16];
#pragma unroll
      for (int ci = 0; ci < 16; ++ci)
        h[ci] = tanhshrink_f(ry * ye_w1[wg * 16 + ci] + ye_b1[wg * 16 + ci]);
#pragma unroll
      for (int i = 0; i < 4; ++i)
        *(float4*)&KB[lane][wg * 16 + 4 * i] = make_float4(h[4*i], h[4*i+1], h[4*i+2], h[4*i+3]);
    }
  }
  __syncthreads();   // B2a: h1 col-chunks from all waves published

  // ---- embed layer 2 -> embs. lane=row, chunked k, SMEM weights, pk over kk
  {
    const int nrow = (s == 0) ? 49 : 48;
    const float* WE = we2 + (s << 12);
    const float* bb = (s == 0) ? xe_b2 : ye_b2;
    if (lane < nrow) {
      v2f o2[16];
#pragma unroll
      for (int ci = 0; ci < 16; ++ci) o2[ci] = mk2(0.f, 0.f);
      for (int kc = 0; kc < 16; ++kc) {
        float4 e = *(const float4*)&KB[lane][kc * 4];     // distinct per lane
        const float* w = WE + (kc << 8) + (wg << 6);      // uniform 256 B
        v2f exy = mk2(e.x, e.y), ezw = mk2(e.z, e.w);
#pragma unroll
        for (int ci = 0; ci < 16; ++ci) {
          o2[ci] = pkfma(exy, *(const v2f*)&w[ci*4+0], o2[ci]);
          o2[ci] = pkfma(ezw, *(const v2f*)&w[ci*4+2], o2[ci]);
        }
      }
      float o[16];
#pragma unroll
      for (int ci = 0; ci < 16; ++ci) o[ci] = bb[wg * 16 + ci] + o2[ci].x + o2[ci].y;
#pragma unroll
      for (int i = 0; i < 4; ++i)
        *(float4*)&embs[lane * 68 + wg * 16 + 4 * i] = make_float4(o[4*i], o[4*i+1], o[4*i+2], o[4*i+3]);
    }
    if (s == 1 && tid < 64) embs[48 * 68 + lane] = learnable_y[lane];
  }
  Hs[grp][lane] = hidden_tokens[grp * 64 + lane];
  __syncthreads();   // B2b: embs published

  // ---- 2 self-attention layers
#pragma unroll 1
  for (int l = 0; l < 2; ++l) {
    const float* Wv_p = Wv + ((l * 2 + s) << 12);
    const float* Wo_p = Wo + ((l * 2 + s) << 12);
    // q: layer 0 precomputed; layer 1 = H @ Wq (wave-local small matmul)
    if (l == 0) {
      qb[grp][lane] = q0g[s * 256 + tid];
    } else {
      const float* Wq_p = Wq + ((l * 2 + s) << 12);
      v2f a2v = mk2(0.f, 0.f);
      for (int k = 0; k < 64; k += 4) {
        float4 hv = *(const float4*)&Hs[grp][k];
        float w0 = Wq_p[(k + 0) * 64 + lane], w1 = Wq_p[(k + 1) * 64 + lane];
        float w2 = Wq_p[(k + 2) * 64 + lane], w3 = Wq_p[(k + 3) * 64 + lane];
        a2v = pkfma(mk2(hv.x, hv.y), mk2(w0, w1), a2v);
        a2v = pkfma(mk2(hv.z, hv.w), mk2(w2, w3), a2v);
      }
      qb[grp][lane] = a2v.x + a2v.y;
    }
    // K = rope(ctx @ Wk): lane=row, chunked k, SMEM weights, pk over kk
    if (lane < 48) {
      v2f o2[16];
#pragma unroll
      for (int ci = 0; ci < 16; ++ci) o2[ci] = mk2(0.f, 0.f);
      const float* WK = wk4 + ((l * 2 + s) << 12);
      for (int kc = 0; kc < 16; ++kc) {
        float4 e = *(const float4*)&embs[lane * 68 + kc * 4];  // distinct per lane
        const float* w = WK + (kc << 8) + (wg << 6);           // uniform 256 B
        v2f exy = mk2(e.x, e.y), ezw = mk2(e.z, e.w);
#pragma unroll
        for (int ci = 0; ci < 16; ++ci) {
          o2[ci] = pkfma(exy, *(const v2f*)&w[ci*4+0], o2[ci]);
          o2[ci] = pkfma(ezw, *(const v2f*)&w[ci*4+2], o2[ci]);
        }
      }
      float o[16];
#pragma unroll
      for (int ci = 0; ci < 16; ++ci) o[ci] = o2[ci].x + o2[ci].y;
      // rope: pairs thread-local; pair index 8wg+i -> p = i&3
      float ko[16];
#pragma unroll
      for (int i = 0; i < 8; ++i) {
        int p = i & 3;
        float co = cs8T[p][lane], si = cs8T[4 + p][lane];
        ko[2*i]   = co * o[2*i] - si * o[2*i+1];
        ko[2*i+1] = si * o[2*i] + co * o[2*i+1];
      }
#pragma unroll
      for (int i = 0; i < 4; ++i)
        *(float4*)&KB[lane][wg * 16 + 4 * i] = make_float4(ko[4*i], ko[4*i+1], ko[4*i+2], ko[4*i+3]);
    }
    __syncthreads();   // B3: K + q published
    // scores + softmax fused (pk dot products)
    {
      const int t0 = tid & 7;
      const int i  = (tid >> 3) & 3;
      const int h  = tid >> 5;
      const int r  = tid >> 3;
      float4 qa = *(const float4*)&qb[i][h * 8];
      float4 qc = *(const float4*)&qb[i][h * 8 + 4];
      float v[6];
#pragma unroll
      for (int j = 0; j < 6; ++j) {
        int t = t0 + 8 * j;
        float4 ka = *(const float4*)&KB[t][h * 8];
        float4 kc = *(const float4*)&KB[t][h * 8 + 4];
        v2f d2 = mk2(0.f, 0.f);
        d2 = pkfma(mk2(qa.x, qa.y), mk2(ka.x, ka.y), d2);
        d2 = pkfma(mk2(qa.z, qa.w), mk2(ka.z, ka.w), d2);
        d2 = pkfma(mk2(qc.x, qc.y), mk2(kc.x, kc.y), d2);
        d2 = pkfma(mk2(qc.z, qc.w), mk2(kc.z, kc.w), d2);
        v[j] = (d2.x + d2.y) * scale - db[t];
      }
      float m = fmaxf(fmaxf(fmaxf(v[0], v[1]), fmaxf(v[2], v[3])), fmaxf(v[4], v[5]));
      m = fmaxf(m, __shfl_xor(m, 1));
      m = fmaxf(m, __shfl_xor(m, 2));
      m = fmaxf(m, __shfl_xor(m, 4));
      float sum = 0.f;
#pragma unroll
      for (int j = 0; j < 6; ++j) { v[j] = __expf(v[j] - m); sum += v[j]; }
      sum += __shfl_xor(sum, 1);
      sum += __shfl_xor(sum, 2);
      sum += __shfl_xor(sum, 4);
      float inv = 1.f / sum;
#pragma unroll
      for (int j = 0; j < 6; ++j) scb[r][t0 + 8 * j] = v[j] * inv;
    }
    __syncthreads();   // B4: probs published; fences KB reads before T writes
    // T = a @ ctx  (32 x 64), rows grp+4m -> KB (wave-local mod-4 rows)
    // pk over t: lo accumulates even t, hi odd t.
    {
      v2f acc2[8];
#pragma unroll
      for (int m = 0; m < 8; ++m) acc2[m] = mk2(0.f, 0.f);
      for (int tt = 0; tt < 48; tt += 4) {
        float e0 = embs[(tt + 0) * 68 + lane], e1 = embs[(tt + 1) * 68 + lane];
        float e2 = embs[(tt + 2) * 68 + lane], e3 = embs[(tt + 3) * 68 + lane];
        v2f e01 = mk2(e0, e1), e23 = mk2(e2, e3);
#pragma unroll
        for (int m = 0; m < 8; ++m) {
          float4 sc4 = *(const float4*)&scb[grp + 4 * m][tt];
          acc2[m] = pkfma(mk2(sc4.x, sc4.y), e01, acc2[m]);
          acc2[m] = pkfma(mk2(sc4.z, sc4.w), e23, acc2[m]);
        }
      }
#pragma unroll
      for (int m = 0; m < 8; ++m) KB[grp + 4 * m][lane] = acc2[m].x + acc2[m].y;
    }
    // no barrier: wave grp reads exactly rows ≡ grp (mod 4) it just wrote
    {
      const int r = ((lane >> 3) << 2) + grp;
      v2f a2v = mk2(0.f, 0.f);
      for (int c = 0; c < 64; c += 4) {
        float4 tv = *(const float4*)&KB[r][c];
        float w0 = Wv_p[(c + 0) * 64 + lane], w1 = Wv_p[(c + 1) * 64 + lane];
        float w2 = Wv_p[(c + 2) * 64 + lane], w3 = Wv_p[(c + 3) * 64 + lane];
        a2v = pkfma(mk2(tv.x, tv.y), mk2(w0, w1), a2v);
        a2v = pkfma(mk2(tv.z, tv.w), mk2(w2, w3), a2v);
      }
      qb[grp][lane] = a2v.x + a2v.y;
    }
    // no barrier: qb row grp wave-local
    {
      v2f a2v = mk2(Hs[grp][lane], 0.f);
      for (int k = 0; k < 64; k += 4) {
        float4 av = *(const float4*)&qb[grp][k];
        float w0 = Wo_p[(k + 0) * 64 + lane], w1 = Wo_p[(k + 1) * 64 + lane];
        float w2 = Wo_p[(k + 2) * 64 + lane], w3 = Wo_p[(k + 3) * 64 + lane];
        a2v = pkfma(mk2(av.x, av.y), mk2(w0, w1), a2v);
        a2v = pkfma(mk2(av.z, av.w), mk2(w2, w3), a2v);
      }
      Hs[grp][lane] = a2v.x + a2v.y;
    }
    if (l == 0) __syncthreads();   // B5a: Wv reads of KB done before l=1 K writes
  }

  // ---- final cross attention
  const float* Wq2_p = Wq2 + (s << 12);
  const float* Wk2_p = Wk2 + (s << 12);
  const float* Wv2_p = Wv2 + (s << 12);
  const float* Wo2_p = Wo2 + (s << 12);
  if (tid < 64) {
    v2f a2v = mk2(0.f, 0.f);
    for (int k = 0; k < 64; k += 4) {
      float4 cv = *(const float4*)&embs[48 * 68 + k];
      float w0 = Wq2_p[(k + 0) * 64 + lane], w1 = Wq2_p[(k + 1) * 64 + lane];
      float w2 = Wq2_p[(k + 2) * 64 + lane], w3 = Wq2_p[(k + 3) * 64 + lane];
      a2v = pkfma(mk2(cv.x, cv.y), mk2(w0, w1), a2v);
      a2v = pkfma(mk2(cv.z, cv.w), mk2(w2, w3), a2v);
    }
    float a = a2v.x + a2v.y;
    float other = __shfl_xor(a, 1);
    int p = (lane >> 1) & 3;
    float co = cs8T[p][48], si = cs8T[4 + p][48];
    q2[lane] = (lane & 1) ? (si * other + co * a) : (co * a - si * other);
  }
  {
    v2f aK2 = mk2(0.f, 0.f), aV2 = mk2(0.f, 0.f);
    for (int k = 0; k < 64; k += 4) {
      float4 hv = *(const float4*)&Hs[grp][k];
      v2f hxy = mk2(hv.x, hv.y), hzw = mk2(hv.z, hv.w);
      float k0 = Wk2_p[(k + 0) * 64 + lane], k1 = Wk2_p[(k + 1) * 64 + lane];
      float k2 = Wk2_p[(k + 2) * 64 + lane], k3 = Wk2_p[(k + 3) * 64 + lane];
      float v0 = Wv2_p[(k + 0) * 64 + lane], v1 = Wv2_p[(k + 1) * 64 + lane];
      float v2 = Wv2_p[(k + 2) * 64 + lane], v3 = Wv2_p[(k + 3) * 64 + lane];
      aK2 = pkfma(hxy, mk2(k0, k1), aK2);
      aK2 = pkfma(hzw, mk2(k2, k3), aK2);
      aV2 = pkfma(hxy, mk2(v0, v1), aV2);
      aV2 = pkfma(hzw, mk2(v2, v3), aV2);
    }
    KB[grp][lane] = aK2.x + aK2.y;      // k2 rows 0..3
    KB[8 + grp][lane] = aV2.x + aV2.y;  // v2 rows 8..11
  }
  __syncthreads();   // B5: k2/v2 + q2 published for wave 0
  if (tid < 32) {
    int h = tid >> 2, i = tid & 3;
    float a = 0.f;
#pragma unroll
    for (int d = 0; d < 8; ++d) a += q2[h * 8 + d] * KB[i][h * 8 + d];
    a *= scale;
    float m = fmaxf(a, __shfl_xor(a, 1));
    m = fmaxf(m, __shfl_xor(m, 2));
    float e = __expf(a - m);
    float sum = e + __shfl_xor(e, 1);
    sum += __shfl_xor(sum, 2);
    a2[tid] = e / sum;
  }
  // wave-0 local from here
  if (tid < 64) {
    int h = lane >> 3;
    float a = 0.f;
#pragma unroll
    for (int i = 0; i < 4; ++i) a += a2[h * 4 + i] * KB[8 + i][lane];
    o1[lane] = a;
  }
  if (tid < 64) {
    v2f a2v = mk2(0.f, 0.f);
    for (int k = 0; k < 64; k += 4) {
      float4 ov = *(const float4*)&o1[k];
      float w0 = Wo2_p[(k + 0) * 64 + lane], w1 = Wo2_p[(k + 1) * 64 + lane];
      float w2 = Wo2_p[(k + 2) * 64 + lane], w3 = Wo2_p[(k + 3) * 64 + lane];
      a2v = pkfma(mk2(ov.x, ov.y), mk2(w0, w1), a2v);
      a2v = pkfma(mk2(ov.z, ov.w), mk2(w2, w3), a2v);
    }
    enc[b * 138 + s * 64 + lane] = a2v.x + a2v.y;
  }
}

// ---------------- decoder: enc(138) -> 512 -> 256 -> 1, 8 batches/block ----
__global__ __launch_bounds__(256, 5) void k_dec(
    const float* __restrict__ enc,
    const float* __restrict__ w0, const float* __restrict__ b0,
    const float* __restrict__ w1, const float* __restrict__ b1,
    const float* __restrict__ w2, const float* __restrict__ b2,
    float* __restrict__ out)
{
  __shared__ float encs[8][140];
  __shared__ float h0s[8][512];
  __shared__ float h1s[8][256];
  const int tid = threadIdx.x;
  const int rb = blockIdx.x * 8;

  for (int i = tid; i < 8 * 138; i += 256) {
    int r = i / 138, k = i - r * 138;
    encs[r][k] = enc[(rb + r) * 138 + k];
  }
  __syncthreads();
  {
    v2f acc0[8], acc1[8];
#pragma unroll
    for (int r = 0; r < 8; ++r) { acc0[r] = mk2(0.f, 0.f); acc1[r] = mk2(0.f, 0.f); }
    for (int k = 0; k < 136; k += 4) {
      float wa0 = w0[(k + 0) * 512 + tid], wa1 = w0[(k + 1) * 512 + tid];
      float wa2 = w0[(k + 2) * 512 + tid], wa3 = w0[(k + 3) * 512 + tid];
      float wb0 = w0[(k + 0) * 512 + tid + 256], wb1 = w0[(k + 1) * 512 + tid + 256];
      float wb2 = w0[(k + 2) * 512 + tid + 256], wb3 = w0[(k + 3) * 512 + tid + 256];
      v2f wa01 = mk2(wa0, wa1), wa23 = mk2(wa2, wa3);
      v2f wb01 = mk2(wb0, wb1), wb23 = mk2(wb2, wb3);
#pragma unroll
      for (int r = 0; r < 8; ++r) {
        float4 ev = *(const float4*)&encs[r][k];
        v2f exy = mk2(ev.x, ev.y), ezw = mk2(ev.z, ev.w);
        acc0[r] = pkfma(exy, wa01, acc0[r]);
        acc0[r] = pkfma(ezw, wa23, acc0[r]);
        acc1[r] = pkfma(exy, wb01, acc1[r]);
        acc1[r] = pkfma(ezw, wb23, acc1[r]);
      }
    }
    const float bb0 = b0[tid], bb1 = b0[tid + 256];
    float t0[8], t1[8];
#pragma unroll
    for (int r = 0; r < 8; ++r) { t0[r] = bb0 + acc0[r].x + acc0[r].y; t1[r] = bb1 + acc1[r].x + acc1[r].y; }
    for (int k = 136; k < 138; ++k) {
      float wa = w0[k * 512 + tid], wb = w0[k * 512 + tid + 256];
#pragma unroll
      for (int r = 0; r < 8; ++r) {
        float e = encs[r][k];
        t0[r] += e * wa; t1[r] += e * wb;
      }
    }
#pragma unroll
    for (int r = 0; r < 8; ++r) {
      h0s[r][tid] = tanhshrink_f(t0[r]);
      h0s[r][tid + 256] = tanhshrink_f(t1[r]);
    }
  }
  __syncthreads();
  {
    v2f acc[8];
#pragma unroll
    for (int r = 0; r < 8; ++r) acc[r] = mk2(0.f, 0.f);
    for (int k = 0; k < 512; k += 4) {
      float ww0 = w1[(k + 0) * 256 + tid], ww1 = w1[(k + 1) * 256 + tid];
      float ww2 = w1[(k + 2) * 256 + tid], ww3 = w1[(k + 3) * 256 + tid];
      v2f w01 = mk2(ww0, ww1), w23 = mk2(ww2, ww3);
#pragma unroll
      for (int r = 0; r < 8; ++r) {
        float4 hv = *(const float4*)&h0s[r][k];
        acc[r] = pkfma(mk2(hv.x, hv.y), w01, acc[r]);
        acc[r] = pkfma(mk2(hv.z, hv.w), w23, acc[r]);
      }
    }
    const float bb = b1[tid];
#pragma unroll
    for (int r = 0; r < 8; ++r) h1s[r][tid] = tanhshrink_f(bb + acc[r].x + acc[r].y);
  }
  __syncthreads();
  {
    int r = tid >> 5, l32 = tid & 31;
    float a = 0.f;
#pragma unroll
    for (int kk = 0; kk < 8; ++kk) {
      int k = l32 + 32 * kk;
      a += h1s[r][k] * w2[k];
    }
    for (int off = 16; off; off >>= 1) a += __shfl_down(a, off, 32);
    if (l32 == 0) out[rb + r] = a + b2[0];
  }
}

extern "C" void kernel_launch(void* const* d_in, const int* in_sizes, int n_in,
                              void* d_out, int out_size, void* d_ws, size_t ws_size,
                              hipStream_t stream) {
  const float* inp        = (const float*)d_in[0];
  const float* dists      = (const float*)d_in[1];
  const float* bn_gamma   = (const float*)d_in[3];
  const float* bn_beta    = (const float*)d_in[4];
  const float* xe_w1      = (const float*)d_in[5];
  const float* xe_b1      = (const float*)d_in[6];
  const float* xe_w2      = (const float*)d_in[7];
  const float* xe_b2      = (const float*)d_in[8];
  const float* ye_w1      = (const float*)d_in[9];
  const float* ye_b1      = (const float*)d_in[10];
  const float* ye_w2      = (const float*)d_in[11];
  const float* ye_b2      = (const float*)d_in[12];
  const float* learnable  = (const float*)d_in[13];
  const float* hidden     = (const float*)d_in[14];
  const float* Wq         = (const float*)d_in[15];
  const float* Wk         = (const float*)d_in[16];
  const float* Wv         = (const float*)d_in[17];
  const float* Wo         = (const float*)d_in[18];
  const float* Wq2        = (const float*)d_in[19];
  const float* Wk2        = (const float*)d_in[20];
  const float* Wv2        = (const float*)d_in[21];
  const float* Wo2        = (const float*)d_in[22];
  const float* dec_w0     = (const float*)d_in[23];
  const float* dec_b0     = (const float*)d_in[24];
  const float* dec_w1     = (const float*)d_in[25];
  const float* dec_b1     = (const float*)d_in[26];
  const float* dec_w2     = (const float*)d_in[27];
  const float* dec_b2     = (const float*)d_in[28];

  double* gsum = (double*)d_ws;                       // 18 doubles @ 0
  float*  bnp  = (float*)((char*)d_ws + 256);         // 18 floats
  float*  q0g  = (float*)((char*)d_ws + 512);         // 512 floats
  float*  enc  = (float*)((char*)d_ws + 2560);        // 8192*138 floats -> ends 4524544
  float*  xw1T = (float*)((char*)d_ws + 4524544);     // 512 floats   (2048 B)
  float*  we2  = (float*)((char*)d_ws + 4526592);     // 8192 floats  (32768 B)
  float*  wk4  = (float*)((char*)d_ws + 4559360);     // 16384 floats (65536 B) -> ends 4624896

  hipMemsetAsync(d_ws, 0, 256, stream);
  k_pack    <<<32, 256, 0, stream>>>(xe_w1, xe_w2, ye_w2, Wk, xw1T, we2, wk4);
  k_stats   <<<512, 256, 0, stream>>>(inp, gsum);
  k_finalize<<<1, 256, 0, stream>>>(gsum, bn_gamma, bn_beta, hidden, Wq, bnp, q0g);
  k_mega    <<<BS * 2, 256, 0, stream>>>(inp, dists, bnp, q0g,
                                         xw1T, xe_b1, we2, xe_b2,
                                         ye_w1, ye_b1, ye_b2,
                                         learnable, hidden,
                                         Wq, wk4, Wv, Wo, Wq2, Wk2, Wv2, Wo2, enc);
  k_dec     <<<BS / 8, 256, 0, stream>>>(enc, dec_w0, dec_b0, dec_w1, dec_b1,
                                         dec_w2, dec_b2, (float*)d_out);
}

// Round 6
// 938.543 us; speedup vs baseline: 1.0026x; 1.0026x over previous
//
#include <hip/hip_runtime.h>
#include <math.h>

#define BS 8192
#define SL 49
#define FDIM 11
#define ROWS (BS*SL)

__device__ __forceinline__ float tanhshrink_f(float x) {
  // x - tanh(x), tanh = 1 - 2/(e^{2x}+1). Robust at +-inf of exp.
  float e = __expf(2.f * x);
  return (x - 1.f) + __fdividef(2.f, e + 1.f);
}

// ---------------- BN stats: sum / sumsq over (BS,SL) for features {0..7,10} ----
__global__ __launch_bounds__(256) void k_stats(const float* __restrict__ inp,
                                               double* __restrict__ gsum) {
  const int nblk = gridDim.x;
  const int per = (ROWS + nblk - 1) / nblk;
  const int r0 = blockIdx.x * per;
  int r1 = r0 + per; if (r1 > ROWS) r1 = ROWS;
  float s[9], q[9];
#pragma unroll
  for (int j = 0; j < 9; ++j) { s[j] = 0.f; q[j] = 0.f; }
  for (int r = r0 + threadIdx.x; r < r1; r += 256) {
    const float* row = inp + r * FDIM;
#pragma unroll
    for (int j = 0; j < 9; ++j) {
      float v = row[j < 8 ? j : 10];
      s[j] += v; q[j] += v * v;
    }
  }
#pragma unroll
  for (int j = 0; j < 9; ++j) {
    for (int off = 32; off; off >>= 1) {
      s[j] += __shfl_down(s[j], off);
      q[j] += __shfl_down(q[j], off);
    }
  }
  __shared__ float red[4][18];
  const int wid = threadIdx.x >> 6;
  const int lane = threadIdx.x & 63;
  if (lane == 0) {
#pragma unroll
    for (int j = 0; j < 9; ++j) { red[wid][j] = s[j]; red[wid][9 + j] = q[j]; }
  }
  __syncthreads();
  if (threadIdx.x < 18) {
    float t = red[0][threadIdx.x] + red[1][threadIdx.x] +
              red[2][threadIdx.x] + red[3][threadIdx.x];
    atomicAdd(&gsum[threadIdx.x], (double)t);
  }
}

// ------- pack kernel: weight relayouts -------
// xw1T[c][k] (64x8); we2[s][kc][c][kk]; wk4[ls][kc][c][kk]  (SMEM-path layouts)
// wpk[m][c4][lane][j] = W_m[(4*c4+j)*64 + lane]  (coalesced dwordx4 streaming)
//   m: 0-3 Wv(l*2+s), 4-7 Wo(l*2+s), 8-9 Wq(l=1,s), 10-11 Wq2, 12-13 Wk2,
//      14-15 Wv2, 16-17 Wo2.
__global__ __launch_bounds__(256) void k_pack(const float* __restrict__ xe_w1,
                          const float* __restrict__ xe_w2,
                          const float* __restrict__ ye_w2,
                          const float* __restrict__ Wk,
                          const float* __restrict__ Wq,
                          const float* __restrict__ Wv,
                          const float* __restrict__ Wo,
                          const float* __restrict__ Wq2,
                          const float* __restrict__ Wk2,
                          const float* __restrict__ Wv2,
                          const float* __restrict__ Wo2,
                          float* __restrict__ xw1T,
                          float* __restrict__ we2,
                          float* __restrict__ wk4,
                          float* __restrict__ wpk) {
  int gid = blockIdx.x * 256 + threadIdx.x;   // 8192 threads
  if (gid < 512) { int cc = gid >> 3, k = gid & 7; xw1T[gid] = xe_w1[k * 64 + cc]; }
  {
    int i = gid;  // 8192 elements, one each
    int ss = i >> 12, r = i & 4095, kc = r >> 8, cc = (r >> 2) & 63, kk = r & 3;
    const float* W2 = ss ? ye_w2 : xe_w2;
    we2[i] = W2[(4 * kc + kk) * 64 + cc];
  }
  for (int i = gid; i < 16384; i += 8192) {
    int ls = i >> 12, r = i & 4095, kc = r >> 8, cc = (r >> 2) & 63, kk = r & 3;
    wk4[i] = Wk[ls * 4096 + (4 * kc + kk) * 64 + cc];
  }
  for (int i = gid; i < 18 * 4096; i += 8192) {
    int m = i >> 12, r = i & 4095, c4 = r >> 8, lane = (r >> 2) & 63, j = r & 3;
    const float* src;
    if      (m < 4)  src = Wv  + (m << 12);
    else if (m < 8)  src = Wo  + ((m - 4) << 12);
    else if (m < 10) src = Wq  + ((2 + (m - 8)) << 12);   // layer-1 Wq
    else if (m < 12) src = Wq2 + ((m - 10) << 12);
    else if (m < 14) src = Wk2 + ((m - 12) << 12);
    else if (m < 16) src = Wv2 + ((m - 14) << 12);
    else             src = Wo2 + ((m - 16) << 12);
    wpk[i] = src[(4 * c4 + j) * 64 + lane];
  }
}

// ---------------- finalize: BN params + layer-0 q (needs gsum) ----------------
__global__ __launch_bounds__(256) void k_finalize(const double* __restrict__ gsum,
                           const float* __restrict__ gamma,
                           const float* __restrict__ beta,
                           const float* __restrict__ hidden,
                           const float* __restrict__ Wq,
                           float* __restrict__ bnp,
                           float* __restrict__ q0g) {
  int tid = threadIdx.x;
  if (tid < 9) {
    const double N = (double)ROWS;
    double mean = gsum[tid] / N;
    double msq  = gsum[9 + tid] / N;
    float var = (float)(msq - mean * mean);
    float sc = gamma[tid] / sqrtf(var + 1e-5f);
    bnp[tid] = sc;
    bnp[9 + tid] = beta[tid] - (float)mean * sc;
  }
  // q0[s][i][c] = sum_k hidden[i][k] * Wq[l=0,s][k][c]
  int s = tid >> 7, i2 = (tid >> 6) & 1, c = tid & 63;
  const float* W = Wq + (s << 12);
#pragma unroll
  for (int ii = 0; ii < 2; ++ii) {
    int i = i2 + 2 * ii;
    float a = 0.f;
    for (int k = 0; k < 64; ++k) a += hidden[i * 64 + k] * W[k * 64 + c];
    q0g[s * 256 + i * 64 + c] = a;
  }
}

// ---------------- mega kernel: one block per (batch, stream) ----------------
// Round-4 structure (scalar fp32 FMA — packed fp32 gains nothing on CDNA4,
// 157.3 TF spec = 1 scalar FMA/lane/cy; r5 measured pkfma slower).
// New: weight-streaming phases (Wv/Wo/Wq-l1/cross) read the wpk [c4][lane][4]
// layout -> coalesced global_load_dwordx4, 16 loads/phase instead of 64.
__global__ __launch_bounds__(256, 4) void k_mega(
    const float* __restrict__ inp, const float* __restrict__ dists,
    const float* __restrict__ bnp, const float* __restrict__ q0g,
    const float* __restrict__ xw1T, const float* __restrict__ xe_b1,
    const float* __restrict__ we2, const float* __restrict__ xe_b2,
    const float* __restrict__ ye_w1, const float* __restrict__ ye_b1,
    const float* __restrict__ ye_b2,
    const float* __restrict__ learnable_y, const float* __restrict__ hidden_tokens,
    const float* __restrict__ wk4, const float* __restrict__ wpk,
    float* __restrict__ enc)
{
  __shared__ float raw[49][12];
  __shared__ float cs8T[8][52];   // [p][t]: per-lane distinct reads
  __shared__ float embs[49 * 68]; // emb, stride 68
  __shared__ float KB[49][68];    // h1, then K (rope'd), then T, then k2/v2
  __shared__ float scb[32][52];   // softmax probs
  __shared__ float Hs[4][64];
  __shared__ float qb[4][64];
  __shared__ float db[48];
  __shared__ float bnl[18];
  __shared__ float q2[64];
  __shared__ float o1[64];
  __shared__ float a2[32];

  const int tid  = threadIdx.x;
  const int lane = tid & 63;
  const int grp  = tid >> 6;
  const int wg   = __builtin_amdgcn_readfirstlane(grp);  // provably wave-uniform
  const int b    = blockIdx.x >> 1;
  const int s    = blockIdx.x & 1;
  const float scale = 0.35355339059327373f;  // 1/sqrt(8)

  // ---- load input rows, bn params, dists
  for (int i = tid; i < 49 * FDIM; i += 256) raw[i / FDIM][i % FDIM] = inp[b * (49*FDIM) + i];
  if (tid < 18) bnl[tid] = bnp[tid];
  if (tid >= 64 && tid < 112) db[tid - 64] = dists[b * 49 + (tid - 64)];
  __syncthreads();   // B1

  // ---- rope trig from RAW features 8,9 ; BN features {0..7,10} in place
  if (tid < 49) {
    float x = raw[tid][8], y = raw[tid][9];
    cs8T[0][tid] = cosf(10.f * x); cs8T[1][tid] = cosf(10.f * y);
    cs8T[2][tid] = cosf(x);        cs8T[3][tid] = cosf(y);
    cs8T[4][tid] = sinf(10.f * x); cs8T[5][tid] = sinf(10.f * y);
    cs8T[6][tid] = sinf(x);        cs8T[7][tid] = sinf(y);
  }
  for (int i = tid; i < 441; i += 256) {   // 49*9
    int t = i / 9, j = i - t * 9;
    int f = (j < 8) ? j : 10;
    raw[t][f] = raw[t][f] * bnl[j] + bnl[9 + j];
  }
  __syncthreads();   // B2

  if (s == 0 && tid < 10) enc[b * 138 + 128 + tid] = raw[48][tid];

  // ---- embed layer 1 -> KB (h1). lane=row, wave wg = cols 16wg..16wg+15
  if (s == 0) {
    if (lane < 49) {
      float4 r0 = *(const float4*)&raw[lane][0];
      float4 r1 = *(const float4*)&raw[lane][4];
      const float* w = xw1T + wg * 128;   // 16 cols x 8 k, contiguous, uniform
      float h[16];
#pragma unroll
      for (int ci = 0; ci < 16; ++ci) {
        float a = xe_b1[wg * 16 + ci]
                + r0.x * w[ci*8+0] + r0.y * w[ci*8+1] + r0.z * w[ci*8+2] + r0.w * w[ci*8+3]
                + r1.x * w[ci*8+4] + r1.y * w[ci*8+5] + r1.z * w[ci*8+6] + r1.w * w[ci*8+7];
        h[ci] = tanhshrink_f(a);
      }
#pragma unroll
      for (int i = 0; i < 4; ++i)
        *(float4*)&KB[lane][wg * 16 + 4 * i] = make_float4(h[4*i], h[4*i+1], h[4*i+2], h[4*i+3]);
    }
  } else {
    if (lane < 48) {
      float ry = raw[lane][10];
      float h[16];
#pragma unroll
      for (int ci = 0; ci < 16; ++ci)
        h[ci] = tanhshrink_f(ry * ye_w1[wg * 16 + ci] + ye_b1[wg * 16 + ci]);
#pragma unroll
      for (int i = 0; i < 4; ++i)
        *(float4*)&KB[lane][wg * 16 + 4 * i] = make_float4(h[4*i], h[4*i+1], h[4*i+2], h[4*i+3]);
    }
  }
  __syncthreads();   // B2a: h1 col-chunks from all waves published

  // ---- embed layer 2 -> embs. lane=row, chunked k, SMEM weights
  {
    const int nrow = (s == 0) ? 49 : 48;
    const float* WE = we2 + (s << 12);
    const float* bb = (s == 0) ? xe_b2 : ye_b2;
    if (lane < nrow) {
      float o[16];
#pragma unroll
      for (int ci = 0; ci < 16; ++ci) o[ci] = bb[wg * 16 + ci];
      for (int kc = 0; kc < 16; ++kc) {
        float4 e = *(const float4*)&KB[lane][kc * 4];     // distinct per lane
        const float* w = WE + (kc << 8) + (wg << 6);      // uniform 256 B
#pragma unroll
        for (int ci = 0; ci < 16; ++ci)
          o[ci] += e.x * w[ci*4+0] + e.y * w[ci*4+1] + e.z * w[ci*4+2] + e.w * w[ci*4+3];
      }
#pragma unroll
      for (int i = 0; i < 4; ++i)
        *(float4*)&embs[lane * 68 + wg * 16 + 4 * i] = make_float4(o[4*i], o[4*i+1], o[4*i+2], o[4*i+3]);
    }
    if (s == 1 && tid < 64) embs[48 * 68 + lane] = learnable_y[lane];
  }
  Hs[grp][lane] = hidden_tokens[grp * 64 + lane];
  __syncthreads();   // B2b: embs published

  // ---- 2 self-attention layers
#pragma unroll 1
  for (int l = 0; l < 2; ++l) {
    // q: layer 0 precomputed; layer 1 = H @ Wq (packed-coalesced weights)
    if (l == 0) {
      qb[grp][lane] = q0g[s * 256 + tid];
    } else {
      const float* WqP = wpk + ((8 + s) << 12);
      float a = 0.f;
      for (int k4 = 0; k4 < 16; ++k4) {
        float4 hv = *(const float4*)&Hs[grp][k4 * 4];
        float4 w  = *(const float4*)&WqP[(k4 << 8) + (lane << 2)];
        a += hv.x * w.x + hv.y * w.y + hv.z * w.z + hv.w * w.w;
      }
      qb[grp][lane] = a;
    }
    // K = rope(ctx @ Wk): lane=row, chunked k, SMEM weights
    if (lane < 48) {
      float o[16];
#pragma unroll
      for (int ci = 0; ci < 16; ++ci) o[ci] = 0.f;
      const float* WK = wk4 + ((l * 2 + s) << 12);
      for (int kc = 0; kc < 16; ++kc) {
        float4 e = *(const float4*)&embs[lane * 68 + kc * 4];  // distinct per lane
        const float* w = WK + (kc << 8) + (wg << 6);           // uniform 256 B
#pragma unroll
        for (int ci = 0; ci < 16; ++ci)
          o[ci] += e.x * w[ci*4+0] + e.y * w[ci*4+1] + e.z * w[ci*4+2] + e.w * w[ci*4+3];
      }
      // rope: pairs thread-local; pair index 8wg+i -> p = i&3
      float ko[16];
#pragma unroll
      for (int i = 0; i < 8; ++i) {
        int p = i & 3;
        float co = cs8T[p][lane], si = cs8T[4 + p][lane];
        ko[2*i]   = co * o[2*i] - si * o[2*i+1];
        ko[2*i+1] = si * o[2*i] + co * o[2*i+1];
      }
#pragma unroll
      for (int i = 0; i < 4; ++i)
        *(float4*)&KB[lane][wg * 16 + 4 * i] = make_float4(ko[4*i], ko[4*i+1], ko[4*i+2], ko[4*i+3]);
    }
    __syncthreads();   // B3: K + q published
    // scores + softmax fused: scores stay in registers, only probs hit LDS
    {
      const int t0 = tid & 7;
      const int i  = (tid >> 3) & 3;
      const int h  = tid >> 5;
      const int r  = tid >> 3;
      float4 qa = *(const float4*)&qb[i][h * 8];
      float4 qc = *(const float4*)&qb[i][h * 8 + 4];
      float v[6];
#pragma unroll
      for (int j = 0; j < 6; ++j) {
        int t = t0 + 8 * j;
        float4 ka = *(const float4*)&KB[t][h * 8];
        float4 kc = *(const float4*)&KB[t][h * 8 + 4];
        float a = qa.x * ka.x + qa.y * ka.y + qa.z * ka.z + qa.w * ka.w
                + qc.x * kc.x + qc.y * kc.y + qc.z * kc.z + qc.w * kc.w;
        v[j] = a * scale - db[t];
      }
      float m = fmaxf(fmaxf(fmaxf(v[0], v[1]), fmaxf(v[2], v[3])), fmaxf(v[4], v[5]));
      m = fmaxf(m, __shfl_xor(m, 1));
      m = fmaxf(m, __shfl_xor(m, 2));
      m = fmaxf(m, __shfl_xor(m, 4));
      float sum = 0.f;
#pragma unroll
      for (int j = 0; j < 6; ++j) { v[j] = __expf(v[j] - m); sum += v[j]; }
      sum += __shfl_xor(sum, 1);
      sum += __shfl_xor(sum, 2);
      sum += __shfl_xor(sum, 4);
      float inv = 1.f / sum;
#pragma unroll
      for (int j = 0; j < 6; ++j) scb[r][t0 + 8 * j] = v[j] * inv;
    }
    __syncthreads();   // B4: probs published; fences KB reads before T writes
    // T = a @ ctx  (32 x 64), rows grp+4m -> KB (wave-local mod-4 rows)
    {
      float acc[8];
#pragma unroll
      for (int m = 0; m < 8; ++m) acc[m] = 0.f;
      for (int tt = 0; tt < 48; tt += 4) {
        float e0 = embs[(tt + 0) * 68 + lane], e1 = embs[(tt + 1) * 68 + lane];
        float e2 = embs[(tt + 2) * 68 + lane], e3 = embs[(tt + 3) * 68 + lane];
#pragma unroll
        for (int m = 0; m < 8; ++m) {
          float4 sc4 = *(const float4*)&scb[grp + 4 * m][tt];
          acc[m] += sc4.x * e0 + sc4.y * e1 + sc4.z * e2 + sc4.w * e3;
        }
      }
#pragma unroll
      for (int m = 0; m < 8; ++m) KB[grp + 4 * m][lane] = acc[m];
    }
    // no barrier: wave grp reads exactly rows ≡ grp (mod 4) it just wrote
    // out = T @ Wv (packed-coalesced weights)
    {
      const float* WvP = wpk + ((l * 2 + s) << 12);
      const int r = ((lane >> 3) << 2) + grp;
      float a = 0.f;
      for (int c4 = 0; c4 < 16; ++c4) {
        float4 tv = *(const float4*)&KB[r][c4 * 4];
        float4 w  = *(const float4*)&WvP[(c4 << 8) + (lane << 2)];
        a += tv.x * w.x + tv.y * w.y + tv.z * w.z + tv.w * w.w;
      }
      qb[grp][lane] = a;
    }
    // no barrier: qb row grp wave-local
    // H += out @ Wo (packed-coalesced weights)
    {
      const float* WoP = wpk + ((4 + l * 2 + s) << 12);
      float a = Hs[grp][lane];
      for (int k4 = 0; k4 < 16; ++k4) {
        float4 av = *(const float4*)&qb[grp][k4 * 4];
        float4 w  = *(const float4*)&WoP[(k4 << 8) + (lane << 2)];
        a += av.x * w.x + av.y * w.y + av.z * w.z + av.w * w.w;
      }
      Hs[grp][lane] = a;
    }
    if (l == 0) __syncthreads();   // B5a: Wv reads of KB done before l=1 K writes
  }

  // ---- final cross attention (packed-coalesced weights)
  if (tid < 64) {
    const float* WqP = wpk + ((10 + s) << 12);
    float a = 0.f;
    for (int k4 = 0; k4 < 16; ++k4) {
      float4 cv = *(const float4*)&embs[48 * 68 + k4 * 4];
      float4 w  = *(const float4*)&WqP[(k4 << 8) + (lane << 2)];
      a += cv.x * w.x + cv.y * w.y + cv.z * w.z + cv.w * w.w;
    }
    float other = __shfl_xor(a, 1);
    int p = (lane >> 1) & 3;
    float co = cs8T[p][48], si = cs8T[4 + p][48];
    q2[lane] = (lane & 1) ? (si * other + co * a) : (co * a - si * other);
  }
  {
    const float* WkP = wpk + ((12 + s) << 12);
    const float* WvP = wpk + ((14 + s) << 12);
    float aK = 0.f, aV = 0.f;
    for (int k4 = 0; k4 < 16; ++k4) {
      float4 hv = *(const float4*)&Hs[grp][k4 * 4];
      float4 wk = *(const float4*)&WkP[(k4 << 8) + (lane << 2)];
      float4 wv = *(const float4*)&WvP[(k4 << 8) + (lane << 2)];
      aK += hv.x * wk.x + hv.y * wk.y + hv.z * wk.z + hv.w * wk.w;
      aV += hv.x * wv.x + hv.y * wv.y + hv.z * wv.z + hv.w * wv.w;
    }
    KB[grp][lane] = aK;      // k2 rows 0..3
    KB[8 + grp][lane] = aV;  // v2 rows 8..11
  }
  __syncthreads();   // B5: k2/v2 + q2 published for wave 0
  if (tid < 32) {
    int h = tid >> 2, i = tid & 3;
    float a = 0.f;
#pragma unroll
    for (int d = 0; d < 8; ++d) a += q2[h * 8 + d] * KB[i][h * 8 + d];
    a *= scale;
    float m = fmaxf(a, __shfl_xor(a, 1));
    m = fmaxf(m, __shfl_xor(m, 2));
    float e = __expf(a - m);
    float sum = e + __shfl_xor(e, 1);
    sum += __shfl_xor(sum, 2);
    a2[tid] = e / sum;
  }
  // wave-0 local from here
  if (tid < 64) {
    int h = lane >> 3;
    float a = 0.f;
#pragma unroll
    for (int i = 0; i < 4; ++i) a += a2[h * 4 + i] * KB[8 + i][lane];
    o1[lane] = a;
  }
  if (tid < 64) {
    const float* WoP = wpk + ((16 + s) << 12);
    float a = 0.f;
    for (int k4 = 0; k4 < 16; ++k4) {
      float4 ov = *(const float4*)&o1[k4 * 4];
      float4 w  = *(const float4*)&WoP[(k4 << 8) + (lane << 2)];
      a += ov.x * w.x + ov.y * w.y + ov.z * w.z + ov.w * w.w;
    }
    enc[b * 138 + s * 64 + lane] = a;
  }
}

// ---------------- decoder: enc(138) -> 512 -> 256 -> 1, 8 batches/block ----
__global__ __launch_bounds__(256, 5) void k_dec(
    const float* __restrict__ enc,
    const float* __restrict__ w0, const float* __restrict__ b0,
    const float* __restrict__ w1, const float* __restrict__ b1,
    const float* __restrict__ w2, const float* __restrict__ b2,
    float* __restrict__ out)
{
  __shared__ float encs[8][140];
  __shared__ float h0s[8][512];
  __shared__ float h1s[8][256];
  const int tid = threadIdx.x;
  const int rb = blockIdx.x * 8;

  for (int i = tid; i < 8 * 138; i += 256) {
    int r = i / 138, k = i - r * 138;
    encs[r][k] = enc[(rb + r) * 138 + k];
  }
  __syncthreads();
  {
    float acc0[8], acc1[8];
    const float bb0 = b0[tid], bb1 = b0[tid + 256];
#pragma unroll
    for (int r = 0; r < 8; ++r) { acc0[r] = bb0; acc1[r] = bb1; }
    for (int k = 0; k < 136; k += 4) {
      float wa0 = w0[(k + 0) * 512 + tid], wa1 = w0[(k + 1) * 512 + tid];
      float wa2 = w0[(k + 2) * 512 + tid], wa3 = w0[(k + 3) * 512 + tid];
      float wb0 = w0[(k + 0) * 512 + tid + 256], wb1 = w0[(k + 1) * 512 + tid + 256];
      float wb2 = w0[(k + 2) * 512 + tid + 256], wb3 = w0[(k + 3) * 512 + tid + 256];
#pragma unroll
      for (int r = 0; r < 8; ++r) {
        float4 ev = *(const float4*)&encs[r][k];
        acc0[r] += ev.x * wa0 + ev.y * wa1 + ev.z * wa2 + ev.w * wa3;
        acc1[r] += ev.x * wb0 + ev.y * wb1 + ev.z * wb2 + ev.w * wb3;
      }
    }
    for (int k = 136; k < 138; ++k) {
      float wa = w0[k * 512 + tid], wb = w0[k * 512 + tid + 256];
#pragma unroll
      for (int r = 0; r < 8; ++r) {
        float e = encs[r][k];
        acc0[r] += e * wa; acc1[r] += e * wb;
      }
    }
#pragma unroll
    for (int r = 0; r < 8; ++r) {
      h0s[r][tid] = tanhshrink_f(acc0[r]);
      h0s[r][tid + 256] = tanhshrink_f(acc1[r]);
    }
  }
  __syncthreads();
  {
    float acc[8];
    const float bb = b1[tid];
#pragma unroll
    for (int r = 0; r < 8; ++r) acc[r] = bb;
    for (int k = 0; k < 512; k += 4) {
      float ww0 = w1[(k + 0) * 256 + tid], ww1 = w1[(k + 1) * 256 + tid];
      float ww2 = w1[(k + 2) * 256 + tid], ww3 = w1[(k + 3) * 256 + tid];
#pragma unroll
      for (int r = 0; r < 8; ++r) {
        float4 hv = *(const float4*)&h0s[r][k];
        acc[r] += hv.x * ww0 + hv.y * ww1 + hv.z * ww2 + hv.w * ww3;
      }
    }
#pragma unroll
    for (int r = 0; r < 8; ++r) h1s[r][tid] = tanhshrink_f(acc[r]);
  }
  __syncthreads();
  {
    int r = tid >> 5, l32 = tid & 31;
    float a = 0.f;
#pragma unroll
    for (int kk = 0; kk < 8; ++kk) {
      int k = l32 + 32 * kk;
      a += h1s[r][k] * w2[k];
    }
    for (int off = 16; off; off >>= 1) a += __shfl_down(a, off, 32);
    if (l32 == 0) out[rb + r] = a + b2[0];
  }
}

extern "C" void kernel_launch(void* const* d_in, const int* in_sizes, int n_in,
                              void* d_out, int out_size, void* d_ws, size_t ws_size,
                              hipStream_t stream) {
  const float* inp        = (const float*)d_in[0];
  const float* dists      = (const float*)d_in[1];
  const float* bn_gamma   = (const float*)d_in[3];
  const float* bn_beta    = (const float*)d_in[4];
  const float* xe_w1      = (const float*)d_in[5];
  const float* xe_b1      = (const float*)d_in[6];
  const float* xe_w2      = (const float*)d_in[7];
  const float* xe_b2      = (const float*)d_in[8];
  const float* ye_w1      = (const float*)d_in[9];
  const float* ye_b1      = (const float*)d_in[10];
  const float* ye_w2      = (const float*)d_in[11];
  const float* ye_b2      = (const float*)d_in[12];
  const float* learnable  = (const float*)d_in[13];
  const float* hidden     = (const float*)d_in[14];
  const float* Wq         = (const float*)d_in[15];
  const float* Wk         = (const float*)d_in[16];
  const float* Wv         = (const float*)d_in[17];
  const float* Wo         = (const float*)d_in[18];
  const float* Wq2        = (const float*)d_in[19];
  const float* Wk2        = (const float*)d_in[20];
  const float* Wv2        = (const float*)d_in[21];
  const float* Wo2        = (const float*)d_in[22];
  const float* dec_w0     = (const float*)d_in[23];
  const float* dec_b0     = (const float*)d_in[24];
  const float* dec_w1     = (const float*)d_in[25];
  const float* dec_b1     = (const float*)d_in[26];
  const float* dec_w2     = (const float*)d_in[27];
  const float* dec_b2     = (const float*)d_in[28];

  double* gsum = (double*)d_ws;                       // 18 doubles @ 0
  float*  bnp  = (float*)((char*)d_ws + 256);         // 18 floats
  float*  q0g  = (float*)((char*)d_ws + 512);         // 512 floats
  float*  enc  = (float*)((char*)d_ws + 2560);        // 8192*138 floats -> ends 4524544
  float*  xw1T = (float*)((char*)d_ws + 4524544);     // 512 floats   (2048 B)
  float*  we2  = (float*)((char*)d_ws + 4526592);     // 8192 floats  (32768 B)
  float*  wk4  = (float*)((char*)d_ws + 4559360);     // 16384 floats (65536 B)
  float*  wpk  = (float*)((char*)d_ws + 4624896);     // 73728 floats (294912 B) -> ends 4919808

  hipMemsetAsync(d_ws, 0, 256, stream);
  k_pack    <<<32, 256, 0, stream>>>(xe_w1, xe_w2, ye_w2, Wk, Wq, Wv, Wo,
                                     Wq2, Wk2, Wv2, Wo2, xw1T, we2, wk4, wpk);
  k_stats   <<<512, 256, 0, stream>>>(inp, gsum);
  k_finalize<<<1, 256, 0, stream>>>(gsum, bn_gamma, bn_beta, hidden, Wq, bnp, q0g);
  k_mega    <<<BS * 2, 256, 0, stream>>>(inp, dists, bnp, q0g,
                                         xw1T, xe_b1, we2, xe_b2,
                                         ye_w1, ye_b1, ye_b2,
                                         learnable, hidden,
                                         wk4, wpk, enc);
  k_dec     <<<BS / 8, 256, 0, stream>>>(enc, dec_w0, dec_b0, dec_w1, dec_b1,
                                         dec_w2, dec_b2, (float*)d_out);
}